// Round 13
// baseline (104.810 us; speedup 1.0000x reference)
//
#include <hip/hip_runtime.h>
#include <hip/hip_bf16.h>

#define B_DIM 16
#define KQ    2048
#define W_DIM 2048
#define D_DIM 128
#define QBLK  64
#define KVB   64
#define NT    (W_DIM / KVB)   // 32
#define KSEG  32768           // K1+K2 LDS bytes per buffer
#define TILEU 24576           // u16 per ws tile (K 32KB + V 32KB)

typedef float f4 __attribute__((ext_vector_type(4)));
typedef float f32x16 __attribute__((ext_vector_type(16)));
typedef __bf16 bf16x8 __attribute__((ext_vector_type(8)));
typedef unsigned short u16x4 __attribute__((ext_vector_type(4)));
typedef unsigned short u16x8 __attribute__((ext_vector_type(8)));

static __device__ __forceinline__ unsigned short f2bf(float x) {
  __bf16 h = (__bf16)x;
  return __builtin_bit_cast(unsigned short, h);
}

// ws tile layout per (b,t), KVB=64:
//   K1 [u16 0,8192):     64 k-rows x 256B; 16B chunk c stored at c' = c ^ (k&7)
//   K2 [u16 8192,16384):  same
//   V  [u16 16384,24576): 16 contiguous 1KB fragments, ch = db*4 + ksl;
//       lane l (=h2*32+l2) slot j = V[k=16*ksl+4*h2+(j&3)+8*(j>>2)][d=db*32+l2]
//       (exact PV B-operand layout -> global->reg, fully coalesced)
__global__ __launch_bounds__(256, 2)
void prepass(const float* __restrict__ K1g, const float* __restrict__ K2g,
             const float* __restrict__ Vg, unsigned short* __restrict__ ws)
{
  __shared__ unsigned short lv[KVB][132];
  const int tid = threadIdx.x;
  const int bt  = blockIdx.x;               // b*NT + t
  const size_t gsrc = (size_t)bt * KVB * D_DIM;
  unsigned short* wt = ws + (size_t)bt * TILEU;

  // ---- K1/K2: convert + chunk-swizzle (64 rows x 16 chunks = 1024 units) ----
#pragma unroll
  for (int uu = 0; uu < 4; ++uu) {
    const int unit = uu * 256 + tid;
    const int k = unit >> 4, c = unit & 15;
    const float* s1 = K1g + gsrc + k * D_DIM + c * 8;
    const float* s2 = K2g + gsrc + k * D_DIM + c * 8;
    f4 a0 = *(const f4*)s1, a1 = *(const f4*)(s1 + 4);
    f4 b0 = *(const f4*)s2, b1 = *(const f4*)(s2 + 4);
    u16x8 o1 = { f2bf(a0[0]), f2bf(a0[1]), f2bf(a0[2]), f2bf(a0[3]),
                 f2bf(a1[0]), f2bf(a1[1]), f2bf(a1[2]), f2bf(a1[3]) };
    u16x8 o2 = { f2bf(b0[0]), f2bf(b0[1]), f2bf(b0[2]), f2bf(b0[3]),
                 f2bf(b1[0]), f2bf(b1[1]), f2bf(b1[2]), f2bf(b1[3]) };
    const int cp = c ^ (k & 7);
    *(u16x8*)(wt + k * 128 + cp * 8)        = o1;
    *(u16x8*)(wt + 8192 + k * 128 + cp * 8) = o2;
  }

  // ---- V: stage bf16 tile (64 rows x 128 d) ----
#pragma unroll
  for (int uu = 0; uu < 8; ++uu) {
    const int fi = uu * 256 + tid;
    const int k = fi >> 5, d4 = (fi & 31) * 4;
    f4 v = *(const f4*)(Vg + gsrc + k * D_DIM + d4);
    *(u16x4*)&lv[k][d4] = (u16x4){ f2bf(v[0]), f2bf(v[1]), f2bf(v[2]), f2bf(v[3]) };
  }
  __syncthreads();

  // ---- V: emit per-fragment contiguous chunks (16 ch x 64 lanes) ----
#pragma unroll
  for (int uu = 0; uu < 4; ++uu) {
    const int unit = uu * 256 + tid;
    const int ch = unit >> 6;     // db*4 + ksl
    const int l  = unit & 63;
    const int ks = ch & 3;
    const int db = ch >> 2;
    const int h2 = l >> 5, l2 = l & 31;
    const int d  = db * 32 + l2;
    u16x8 ov;
#pragma unroll
    for (int j = 0; j < 8; ++j) {
      const int k = 16 * ks + 4 * h2 + (j & 3) + 8 * (j >> 2);
      ov[j] = lv[k][d];
    }
    *(u16x8*)(wt + 16384 + ch * 512 + l * 8) = ov;
  }
}

// ---------------- main: KVB=64, K via LDS dbuf, V via global->reg ----------------
// Per iter: STAGE K(t+1) [8 gload_lds] -> vmcnt(16) -> burst { PV(t-1) [16 MFMA,
// reg-only] + QK(t) [16 ds_read + 16 MFMA, 4 partial chains] } -> exp(32) ->
// V(t) global->reg [16 dwordx4] -> lgkmcnt(0) + barrier.
// PV-before-QK keeps peak VGPR ~205 (vvC+paP die before sa goes live).
__global__ __launch_bounds__(256, 2)
void diffattn(const float* __restrict__ Q1g, const float* __restrict__ Q2g,
              const unsigned short* __restrict__ ws,
              const float* __restrict__ lamp, float* __restrict__ Og)
{
  __shared__ char smem[2 * KSEG];   // 64KB: 2 K buffers; epilogue reuses [0,32K)

  const int tid  = threadIdx.x;
  const int wv   = tid >> 6;     // 0..3
  const int lane = tid & 63;
  const int hi   = lane >> 5;
  const int ln   = lane & 31;
  const int s    = wv & 1;       // stream
  const int qh   = wv >> 1;      // q chunk (32 rows)

  // XCD-aware bijective swizzle: 512 = 8 XCDs x 64
  const int wg  = blockIdx.x;
  const int swz = (wg & 7) * 64 + (wg >> 3);
  const int qt  = swz & 31;
  const int b   = swz >> 5;
  const int q0  = qt * QBLK;

  const float qscale = 0.08838834764831845f * 1.4426950408889634f; // 1/sqrt(128)*log2(e)

  // ---- Q fragments (B-operand): lane = q-col ln, d-slots hi*8+j+16*step
  const float* Qs = s ? Q2g : Q1g;
  bf16x8 qf[8];
  {
    const float* qp = Qs + ((size_t)b * KQ + q0 + qh * 32 + ln) * D_DIM + hi * 8;
#pragma unroll
    for (int st = 0; st < 8; ++st) {
      f4 lo = *(const f4*)(qp + st * 16);
      f4 h4 = *(const f4*)(qp + st * 16 + 4);
      bf16x8 tq;
#pragma unroll
      for (int j = 0; j < 4; ++j) {
        tq[j]     = (__bf16)(lo[j] * qscale);
        tq[4 + j] = (__bf16)(h4[j] * qscale);
      }
      qf[st] = tq;
    }
  }

  f32x16 o[4];
#pragma unroll
  for (int db = 0; db < 4; ++db)
#pragma unroll
    for (int i = 0; i < 16; ++i) o[db][i] = 0.f;

  float lsp[4] = {0.f, 0.f, 0.f, 0.f};

  // ---- addresses ----
  const unsigned short* wsb = ws + (size_t)b * NT * TILEU;
  const int kbase = s * 16384 + ln * 256;   // K1/K2 select + row
  int koff[8];
#pragma unroll
  for (int st = 0; st < 8; ++st)
    koff[st] = ((2 * st + hi) ^ (ln & 7)) << 4;

  auto STAGE = [&](int t, char* dB) {
    const unsigned short* sp0 = wsb + (size_t)t * TILEU + lane * 8;
#pragma unroll
    for (int i = 0; i < 8; ++i) {
      const int ch = wv * 8 + i;
      __builtin_amdgcn_global_load_lds(
          (const __attribute__((address_space(1))) void*)(sp0 + ch * 512),
          (__attribute__((address_space(3))) void*)(dB + ch * 1024), 16, 0, 0);
    }
  };

  STAGE(0, smem);
  __builtin_amdgcn_sched_barrier(0);
  asm volatile("s_waitcnt vmcnt(0)" ::: "memory");
  __builtin_amdgcn_s_barrier();
  __builtin_amdgcn_sched_barrier(0);

  bf16x8 paP[4];   // P fragments of tile t-1 (ksl = 0..3)
  bf16x8 vvC[16];  // V fragments of tile t-1 (global->reg, idx = db*4+ksl)

#pragma unroll 1
  for (int t = 0; t < NT; ++t) {
    char* bufc = smem + (t & 1) * KSEG;
    if (t + 1 < NT) STAGE(t + 1, smem + ((t + 1) & 1) * KSEG);

    // stage(t) must be resident before any ds_read of bufc:
    // normal iters: 32 outstanding -> 16 drains stage(t) (+half V(t-1));
    // tail iter:    24 outstanding -> 16 drains stage(NT-1). Conservative-safe.
    __builtin_amdgcn_sched_barrier(0);
    asm volatile("s_waitcnt vmcnt(16)" ::: "memory");
    __builtin_amdgcn_sched_barrier(0);

    __builtin_amdgcn_s_setprio(1);
    // ---- PV(t-1): reg-only, frees vvC/paP early ----
    if (t) {
#pragma unroll
      for (int db = 0; db < 4; ++db)
#pragma unroll
        for (int ksl = 0; ksl < 4; ++ksl)
          o[db] = __builtin_amdgcn_mfma_f32_32x32x16_bf16(paP[ksl], vvC[db * 4 + ksl], o[db], 0, 0, 0);
    }
    // ---- QK(t): S[64 kr][32 q], 4 independent partial chains ----
    f32x16 s0, s1, s2, s3;
#pragma unroll
    for (int i = 0; i < 16; ++i) { s0[i] = 0.f; s1[i] = 0.f; s2[i] = 0.f; s3[i] = 0.f; }
#pragma unroll
    for (int st = 0; st < 4; ++st) {
      const bf16x8 a0 = *(const bf16x8*)(bufc + kbase + koff[st]);
      const bf16x8 a1 = *(const bf16x8*)(bufc + kbase + koff[st + 4]);
      const bf16x8 a2 = *(const bf16x8*)(bufc + kbase + 8192 + koff[st]);
      const bf16x8 a3 = *(const bf16x8*)(bufc + kbase + 8192 + koff[st + 4]);
      s0 = __builtin_amdgcn_mfma_f32_32x32x16_bf16(a0, qf[st], s0, 0, 0, 0);
      s1 = __builtin_amdgcn_mfma_f32_32x32x16_bf16(a1, qf[st + 4], s1, 0, 0, 0);
      s2 = __builtin_amdgcn_mfma_f32_32x32x16_bf16(a2, qf[st], s2, 0, 0, 0);
      s3 = __builtin_amdgcn_mfma_f32_32x32x16_bf16(a3, qf[st + 4], s3, 0, 0, 0);
    }
    __builtin_amdgcn_s_setprio(0);

    // ---- unnormalized exp2 (raw v_exp_f32); P packed into A-fragments ----
    // sa(kh0) = s0+s1, sa(kh1) = s2+s3; paP[ksl= kh*2 + (j>=8)][j&7]
#pragma unroll
    for (int j = 0; j < 16; ++j) {
      const float p0 = __builtin_amdgcn_exp2f(s0[j] + s1[j]);
      const float p1 = __builtin_amdgcn_exp2f(s2[j] + s3[j]);
      lsp[j & 3] += p0 + p1;
      paP[(j >> 3)][j & 7]     = (__bf16)p0;   // kh0 -> ksl 0,1
      paP[2 + (j >> 3)][j & 7] = (__bf16)p1;   // kh1 -> ksl 2,3
    }

    // ---- V(t) fragments: global->reg, consumed next iter ----
    {
      const unsigned short* vt = wsb + (size_t)t * TILEU + 16384 + lane * 8;
#pragma unroll
      for (int ch = 0; ch < 16; ++ch)
        vvC[ch] = *(const bf16x8*)(vt + ch * 512);
    }

    __builtin_amdgcn_sched_barrier(0);
    asm volatile("s_waitcnt lgkmcnt(0)" ::: "memory");
    __builtin_amdgcn_s_barrier();
    __builtin_amdgcn_sched_barrier(0);
  }

  // ---- final PV for tile NT-1 (compiler waits the V loads) ----
#pragma unroll
  for (int db = 0; db < 4; ++db)
#pragma unroll
    for (int ksl = 0; ksl < 4; ++ksl)
      o[db] = __builtin_amdgcn_mfma_f32_32x32x16_bf16(paP[ksl], vvC[db * 4 + ksl], o[db], 0, 0, 0);

  asm volatile("s_waitcnt vmcnt(0)" ::: "memory");   // drain any straggler stages

  // ---- epilogue: reduce l, combine streams via LDS [0,32K) ----
  const float lam = 1.f / (1.f + __expf(-lamp[0]));
  float ls = (lsp[0] + lsp[1]) + (lsp[2] + lsp[3]);
  const float lt  = ls + __shfl_xor(ls, 32);
  const float fac = s ? lam : 1.f;
  float wq[16];
#pragma unroll
  for (int r = 0; r < 16; ++r)
    wq[r] = fac / __shfl(lt, (r & 3) + 8 * (r >> 2) + 4 * hi);

  if (s == 1) {
#pragma unroll
    for (int db = 0; db < 4; ++db)
#pragma unroll
      for (int r = 0; r < 16; ++r) {
        const int q = qh * 32 + (r & 3) + 8 * (r >> 2) + 4 * hi;
        *(float*)(smem + q * 512 + (db * 32 + ln) * 4) = o[db][r] * wq[r];
      }
  }
  __syncthreads();
  if (s == 0) {
    float* op = Og + ((size_t)b * KQ + q0) * D_DIM;
#pragma unroll
    for (int db = 0; db < 4; ++db)
#pragma unroll
      for (int r = 0; r < 16; ++r) {
        const int q = qh * 32 + (r & 3) + 8 * (r >> 2) + 4 * hi;
        const float o2v = *(const float*)(smem + q * 512 + (db * 32 + ln) * 4);
        op[q * D_DIM + db * 32 + ln] = o[db][r] * wq[r] - o2v;
      }
  }
}

extern "C" void kernel_launch(void* const* d_in, const int* in_sizes, int n_in,
                              void* d_out, int out_size, void* d_ws, size_t ws_size,
                              hipStream_t stream) {
  const float* Q1 = (const float*)d_in[0];
  const float* Q2 = (const float*)d_in[1];
  const float* K1 = (const float*)d_in[2];
  const float* K2 = (const float*)d_in[3];
  const float* V  = (const float*)d_in[4];
  const float* lm = (const float*)d_in[5];
  float* O = (float*)d_out;

  unsigned short* wsp = (unsigned short*)d_ws;   // 24 MB

  prepass<<<dim3(B_DIM * NT), dim3(256), 0, stream>>>(K1, K2, V, wsp);
  diffattn<<<dim3(B_DIM * (KQ / QBLK)), dim3(256), 0, stream>>>(Q1, Q2, wsp, lm, O);
}

// Round 14
// 98.449 us; speedup vs baseline: 1.0646x; 1.0646x over previous
//
#include <hip/hip_runtime.h>
#include <hip/hip_bf16.h>

#define B_DIM 16
#define KQ    2048
#define W_DIM 2048
#define D_DIM 128
#define QBLK  64
#define KVB   32
#define NT    (W_DIM / KVB)   // 64
#define TILEU 12288           // u16 per ws tile: K 16 frags + V 8 frags, 1KB each

typedef float f4 __attribute__((ext_vector_type(4)));
typedef float f32x16 __attribute__((ext_vector_type(16)));
typedef __bf16 bf16x8 __attribute__((ext_vector_type(8)));
typedef unsigned short u16x4 __attribute__((ext_vector_type(4)));
typedef unsigned short u16x8 __attribute__((ext_vector_type(8)));

static __device__ __forceinline__ unsigned short f2bf(float x) {
  __bf16 h = (__bf16)x;
  return __builtin_bit_cast(unsigned short, h);
}

// ws tile layout per (b,t): 24 fragment chunks of 1KB, each the EXACT register
// image of one MFMA operand fragment for a 64-lane wave (lane l owns 16B at
// chunk + l*16):
//   K frags  [u16 0,8192):  ch = s*8+st; lane l=(hi,ln): K_s[k=ln][d = st*16+hi*8 ..+8]
//   V frags  [u16 8192,12288): ch = db*2+ks; lane l: slot j = V[k=16ks+4hi+(j&3)+8(j>>2)][d=db*32+ln]
// (V uses the same k-permutation pi as the P packing -> contraction consistent)
__global__ __launch_bounds__(256, 2)
void prepass(const float* __restrict__ K1g, const float* __restrict__ K2g,
             const float* __restrict__ Vg, unsigned short* __restrict__ ws)
{
  __shared__ unsigned short lv[KVB][132];
  const int tid = threadIdx.x;
  const int bt  = blockIdx.x;               // b*NT + t
  const size_t gsrc = (size_t)bt * KVB * D_DIM;
  unsigned short* wt = ws + (size_t)bt * TILEU;

  // ---- K fragments: 16 chunks x 64 lanes = 1024 units ----
#pragma unroll
  for (int uu = 0; uu < 4; ++uu) {
    const int unit = uu * 256 + tid;
    const int ch = unit >> 6, l = unit & 63;
    const int sK = ch >> 3, st = ch & 7;
    const int h2 = l >> 5, l2 = l & 31;
    const float* src = (sK ? K2g : K1g) + gsrc + l2 * D_DIM + st * 16 + h2 * 8;
    f4 a0 = *(const f4*)src, a1 = *(const f4*)(src + 4);
    u16x8 o1 = { f2bf(a0[0]), f2bf(a0[1]), f2bf(a0[2]), f2bf(a0[3]),
                 f2bf(a1[0]), f2bf(a1[1]), f2bf(a1[2]), f2bf(a1[3]) };
    *(u16x8*)(wt + unit * 8) = o1;
  }

  // ---- V: stage bf16 tile ----
#pragma unroll
  for (int uu = 0; uu < 4; ++uu) {
    const int fi = uu * 256 + tid;
    const int k = fi >> 5, d4 = (fi & 31) * 4;
    f4 v = *(const f4*)(Vg + gsrc + k * D_DIM + d4);
    *(u16x4*)&lv[k][d4] = (u16x4){ f2bf(v[0]), f2bf(v[1]), f2bf(v[2]), f2bf(v[3]) };
  }
  __syncthreads();

  // ---- V fragments: 8 chunks x 64 lanes = 512 units ----
#pragma unroll
  for (int uu = 0; uu < 2; ++uu) {
    const int unit = uu * 256 + tid;
    const int ch = unit >> 6, l = unit & 63;
    const int ks = ch & 1, db = ch >> 1;
    const int h2 = l >> 5, l2 = l & 31;
    const int d  = db * 32 + l2;
    u16x8 ov;
#pragma unroll
    for (int j = 0; j < 8; ++j) {
      const int k = 16 * ks + 4 * h2 + (j & 3) + 8 * (j >> 2);
      ov[j] = lv[k][d];
    }
    *(u16x8*)(wt + 8192 + unit * 8) = ov;
  }
}

// ---------------- main: zero-barrier loop, all operands global->reg ----------------
// Per wave-iter: 16 coalesced dwordx4 loads (L2-resident ws) -> QK (8 MFMA,
// 2 chains) -> exp2 -> PV (8 MFMA). No LDS, no barriers, no waitcnt asm in
// the loop: waves drift freely, cross-wave overlap replaces lockstep phases.
__global__ __launch_bounds__(256, 2)
void diffattn(const float* __restrict__ Q1g, const float* __restrict__ Q2g,
              const unsigned short* __restrict__ ws,
              const float* __restrict__ lamp, float* __restrict__ Og)
{
  __shared__ char smem[32768];   // epilogue combine only

  const int tid  = threadIdx.x;
  const int wv   = tid >> 6;     // 0..3
  const int lane = tid & 63;
  const int hi   = lane >> 5;
  const int ln   = lane & 31;
  const int s    = wv & 1;       // stream
  const int qh   = wv >> 1;      // q chunk (32 rows)

  // XCD-aware bijective swizzle: 512 = 8 XCDs x 64
  const int wg  = blockIdx.x;
  const int swz = (wg & 7) * 64 + (wg >> 3);
  const int qt  = swz & 31;
  const int b   = swz >> 5;
  const int q0  = qt * QBLK;

  const float qscale = 0.08838834764831845f * 1.4426950408889634f; // 1/sqrt(128)*log2(e)

  // ---- Q fragments (B-operand): lane = q-col ln, d-slots hi*8+j+16*step
  const float* Qs = s ? Q2g : Q1g;
  bf16x8 qf[8];
  {
    const float* qp = Qs + ((size_t)b * KQ + q0 + qh * 32 + ln) * D_DIM + hi * 8;
#pragma unroll
    for (int st = 0; st < 8; ++st) {
      f4 lo = *(const f4*)(qp + st * 16);
      f4 h4 = *(const f4*)(qp + st * 16 + 4);
      bf16x8 tq;
#pragma unroll
      for (int j = 0; j < 4; ++j) {
        tq[j]     = (__bf16)(lo[j] * qscale);
        tq[4 + j] = (__bf16)(h4[j] * qscale);
      }
      qf[st] = tq;
    }
  }

  f32x16 o[4];
#pragma unroll
  for (int db = 0; db < 4; ++db)
#pragma unroll
    for (int i = 0; i < 16; ++i) o[db][i] = 0.f;

  float lsp[2] = {0.f, 0.f};

  const unsigned short* wsb = ws + (size_t)b * NT * TILEU;
  const unsigned short* kfp = wsb + (size_t)(s * 8) * 512 + lane * 8;  // this stream's K frags
  const unsigned short* vfp = wsb + 8192 + lane * 8;

#pragma unroll 1
  for (int t = 0; t < NT; ++t) {
    const size_t toff = (size_t)t * TILEU;

    // ---- fragment loads (all issued up front; compiler inserts the waits) ----
    bf16x8 kf[8], vf[8];
#pragma unroll
    for (int st = 0; st < 8; ++st)
      kf[st] = *(const bf16x8*)(kfp + toff + st * 512);
#pragma unroll
    for (int ch = 0; ch < 8; ++ch)
      vf[ch] = *(const bf16x8*)(vfp + toff + ch * 512);

    // ---- QK: S[k-row][q=ln], two partial chains over d ----
    f32x16 s0, s1;
#pragma unroll
    for (int i = 0; i < 16; ++i) { s0[i] = 0.f; s1[i] = 0.f; }
    __builtin_amdgcn_s_setprio(1);
#pragma unroll
    for (int st = 0; st < 4; ++st) {
      s0 = __builtin_amdgcn_mfma_f32_32x32x16_bf16(kf[st],     qf[st],     s0, 0, 0, 0);
      s1 = __builtin_amdgcn_mfma_f32_32x32x16_bf16(kf[st + 4], qf[st + 4], s1, 0, 0, 0);
    }
    __builtin_amdgcn_s_setprio(0);

    // ---- unnormalized exp2 (raw v_exp_f32); P packed into A-fragments ----
    bf16x8 pa[2];
#pragma unroll
    for (int ks = 0; ks < 2; ++ks) {
      bf16x8 pv;
#pragma unroll
      for (int j = 0; j < 8; ++j) {
        const float p = __builtin_amdgcn_exp2f(s0[8 * ks + j] + s1[8 * ks + j]);
        lsp[j & 1] += p;
        pv[j] = (__bf16)p;    // slot j <-> k = 16ks + 4hi + (j&3) + 8(j>>2)
      }
      pa[ks] = pv;
    }

    // ---- PV: O[q][d] ----
    __builtin_amdgcn_s_setprio(1);
#pragma unroll
    for (int db = 0; db < 4; ++db)
#pragma unroll
      for (int ks = 0; ks < 2; ++ks)
        o[db] = __builtin_amdgcn_mfma_f32_32x32x16_bf16(pa[ks], vf[db * 2 + ks], o[db], 0, 0, 0);
    __builtin_amdgcn_s_setprio(0);
  }

  // ---- epilogue: reduce l, combine streams via LDS ----
  const float lam = 1.f / (1.f + __expf(-lamp[0]));
  float ls = lsp[0] + lsp[1];
  const float lt  = ls + __shfl_xor(ls, 32);
  const float fac = s ? lam : 1.f;
  float wq[16];
#pragma unroll
  for (int r = 0; r < 16; ++r)
    wq[r] = fac / __shfl(lt, (r & 3) + 8 * (r >> 2) + 4 * hi);

  if (s == 1) {
#pragma unroll
    for (int db = 0; db < 4; ++db)
#pragma unroll
      for (int r = 0; r < 16; ++r) {
        const int q = qh * 32 + (r & 3) + 8 * (r >> 2) + 4 * hi;
        *(float*)(smem + q * 512 + (db * 32 + ln) * 4) = o[db][r] * wq[r];
      }
  }
  __syncthreads();
  if (s == 0) {
    float* op = Og + ((size_t)b * KQ + q0) * D_DIM;
#pragma unroll
    for (int db = 0; db < 4; ++db)
#pragma unroll
      for (int r = 0; r < 16; ++r) {
        const int q = qh * 32 + (r & 3) + 8 * (r >> 2) + 4 * hi;
        const float o2v = *(const float*)(smem + q * 512 + (db * 32 + ln) * 4);
        op[q * D_DIM + db * 32 + ln] = o[db][r] * wq[r] - o2v;
      }
  }
}

extern "C" void kernel_launch(void* const* d_in, const int* in_sizes, int n_in,
                              void* d_out, int out_size, void* d_ws, size_t ws_size,
                              hipStream_t stream) {
  const float* Q1 = (const float*)d_in[0];
  const float* Q2 = (const float*)d_in[1];
  const float* K1 = (const float*)d_in[2];
  const float* K2 = (const float*)d_in[3];
  const float* V  = (const float*)d_in[4];
  const float* lm = (const float*)d_in[5];
  float* O = (float*)d_out;

  unsigned short* wsp = (unsigned short*)d_ws;   // 24 MB

  prepass<<<dim3(B_DIM * NT), dim3(256), 0, stream>>>(K1, K2, V, wsp);
  diffattn<<<dim3(B_DIM * (KQ / QBLK)), dim3(256), 0, stream>>>(Q1, Q2, wsp, lm, O);
}